// Round 4
// baseline (320.925 us; speedup 1.0000x reference)
//
#include <hip/hip_runtime.h>

// B=32, C=64, H=W=112. Per-sample 3x3 convs via bf16 MFMA implicit GEMM.
// Per sample GEMM: M=64 (cout), K=576 (cin*9), N=12544 (pixels).
// Block: 16x16 output tile, 4 waves x 4 rows, 18x18x64 halo tile in LDS.
// A (weights) hand-prefetched distance-2 in registers; epilogue LDS-bounce.
#define HW    112
#define HW2   12544
#define CH    64
#define NB    32
#define TS    16
#define HP    18
#define NPIX  324           // 18*18 halo pixels
#define NPC   (NB*HW2)      // per-channel count for BN stats

using u16 = unsigned short;
typedef __attribute__((ext_vector_type(8))) short bf16x8;   // 8 bf16 = 4 VGPRs
typedef __attribute__((ext_vector_type(4))) float f32x4;

__device__ __forceinline__ float b2f(u16 u) {
    union { unsigned int i; float f; } c;
    c.i = ((unsigned int)u) << 16;
    return c.f;
}
__device__ __forceinline__ u16 f2b(float f) {
    union { float f; unsigned int i; } c;
    c.f = f;
    unsigned int x = c.i;
    x += 0x7fffu + ((x >> 16) & 1u);   // RNE
    return (u16)(x >> 16);
}

// LDS tile: [pix][ci 0..63] bf16, 128 B per pixel row.
// XOR-swizzle byte bits 4-6 with pix&7: conflict-free ds_read/write_b128.
__device__ __forceinline__ int swz(int pix, int ci) {
    return (pix * 128 + ci * 2) ^ ((pix & 7) << 4);
}

// MODE 0: input = raw f32 x [b][ci][y][x]   (conv1)
// MODE 1: input = bf16 out1 [b][y][x][ci] with BN1 affine + ReLU fused (conv2)
// wt: bf16 [b][tap][co][ci]. out: bf16 [b][y][x][co]. sums: 128 floats (sum,sumsq).
template<int MODE>
__global__ __launch_bounds__(256, 3)
void conv_mfma(const float* __restrict__ xf, const u16* __restrict__ xb,
               const u16* __restrict__ wt, const float* __restrict__ sbp,
               u16* __restrict__ out, float* __restrict__ sums)
{
    __shared__ u16 xt[NPIX * CH];                 // 41472 B
    // XCD swizzle: 1568 blocks = 8 XCD x 196; consecutive ids same sample.
    const int bid = (int)blockIdx.x;
    const int sid = (bid & 7) * 196 + (bid >> 3);
    const int b   = sid / 49;
    const int rem = sid - b * 49;
    const int ty0 = (rem / 7) * TS, tx0 = (rem % 7) * TS;
    const int tid  = threadIdx.x;
    const int lane = tid & 63, wave = tid >> 6;
    const int px = lane & 15, kg = lane >> 4;
    const int y0 = wave * 4;

    // ---- stage 18x18x64 input tile into LDS (pixel-major, swizzled) ----
    if (MODE == 0) {
        for (int t = tid; t < NPIX * 8; t += 256) {
            int g  = t / NPIX;               // ci group (8 ci)
            int r  = t - g * NPIX;           // pixel in tile
            int iy = r / HP, ix = r - iy * HP;
            int gy = ty0 + iy - 1, gx = tx0 + ix - 1;
            bf16x8 pk = (bf16x8)0;
            if (((unsigned)gy < HW) && ((unsigned)gx < HW)) {
                const float* src = xf + ((size_t)b * CH + g * 8) * HW2 + gy * HW + gx;
#pragma unroll
                for (int j = 0; j < 8; ++j)
                    pk[j] = (short)f2b(src[(size_t)j * HW2]);
            }
            *(bf16x8*)((char*)xt + swz(r, g * 8)) = pk;
        }
    } else {
        const int j8 = (tid & 7) * 8;        // lane-fixed channel chunk
        float sc[8], bi[8];
#pragma unroll
        for (int e = 0; e < 8; ++e) { sc[e] = sbp[j8 + e]; bi[e] = sbp[64 + j8 + e]; }
        for (int t = tid; t < NPIX * 8; t += 256) {
            int p  = t >> 3;                 // pixel in tile
            int iy = p / HP, ix = p - iy * HP;
            int gy = ty0 + iy - 1, gx = tx0 + ix - 1;
            bf16x8 pk = (bf16x8)0;
            if (((unsigned)gy < HW) && ((unsigned)gx < HW)) {
                bf16x8 v = *(const bf16x8*)(xb + ((size_t)b * HW2 + (size_t)gy * HW + gx) * CH + j8);
#pragma unroll
                for (int e = 0; e < 8; ++e) {
                    float tv = b2f((u16)v[e]) * sc[e] + bi[e];
                    pk[e] = (short)f2b(tv > 0.f ? tv : 0.f);
                }
            }
            *(bf16x8*)((char*)xt + swz(p, j8)) = pk;
        }
    }

    // ---- A-fragment prefetch (distance 2, 3 register buffers) ----
    const u16* wtb = wt + (size_t)b * 9 * CH * CH;
    const int arow = px * CH + kg * 8;       // co=(m*16+px), ci=kg*8 (+kc*32)
    bf16x8 afb[3][4];
#pragma unroll
    for (int m = 0; m < 4; ++m) afb[0][m] = *(const bf16x8*)(wtb + arow + m * 16 * CH);
#pragma unroll
    for (int m = 0; m < 4; ++m) afb[1][m] = *(const bf16x8*)(wtb + 32 + arow + m * 16 * CH);

    f32x4 acc[4][4];
#pragma unroll
    for (int r = 0; r < 4; ++r)
#pragma unroll
        for (int m = 0; m < 4; ++m) acc[r][m] = (f32x4)0.f;

    __syncthreads();

    // ---- main loop: 18 k-steps (9 taps x 2 ci-halves), fully unrolled ----
#pragma unroll
    for (int s = 0; s < 18; ++s) {
        if (s + 2 < 18) {
            const int s2 = s + 2;
            const u16* wp = wtb + (s2 >> 1) * (CH * CH) + (s2 & 1) * 32 + arow;
#pragma unroll
            for (int m = 0; m < 4; ++m)
                afb[s2 % 3][m] = *(const bf16x8*)(wp + m * 16 * CH);
        }
        const int tap = s >> 1, dy = tap / 3, dx = tap % 3;
        const int ci0 = (s & 1) * 32 + kg * 8;
#pragma unroll
        for (int r = 0; r < 4; ++r) {
            const int pr = (y0 + r + dy) * HP + px + dx;
            bf16x8 bfr = *(const bf16x8*)((const char*)xt + swz(pr, ci0));
#pragma unroll
            for (int m = 0; m < 4; ++m)
                acc[r][m] = __builtin_amdgcn_mfma_f32_16x16x32_bf16(afb[s % 3][m], bfr, acc[r][m], 0, 0, 0);
        }
    }

    // ---- epilogue: LDS bounce -> contiguous 16B/lane stores + BN partials ----
    __syncthreads();                          // all waves done reading xt
    float s_[4][4], sq[4][4];
#pragma unroll
    for (int m = 0; m < 4; ++m)
#pragma unroll
        for (int q = 0; q < 4; ++q) { s_[m][q] = 0.f; sq[m][q] = 0.f; }

    char* bw = (char*)xt + wave * 8192;       // private 8KB bounce per wave
#pragma unroll
    for (int r = 0; r < 4; ++r) {
#pragma unroll
        for (int m = 0; m < 4; ++m) {
            float v0 = acc[r][m][0], v1 = acc[r][m][1], v2 = acc[r][m][2], v3 = acc[r][m][3];
            s_[m][0] += v0; s_[m][1] += v1; s_[m][2] += v2; s_[m][3] += v3;
            sq[m][0] += v0 * v0; sq[m][1] += v1 * v1; sq[m][2] += v2 * v2; sq[m][3] += v3 * v3;
            uint2 pk;
            pk.x = ((unsigned)f2b(v1) << 16) | f2b(v0);
            pk.y = ((unsigned)f2b(v3) << 16) | f2b(v2);
            *(uint2*)(bw + ((r * 2048 + px * 128 + m * 32 + kg * 8) ^ ((px & 7) << 4))) = pk;
        }
    }
    const int jc = lane & 7, pp = lane >> 3;
#pragma unroll
    for (int r = 0; r < 4; ++r) {
        u16* og = out + ((size_t)b * HW2 + (size_t)(ty0 + y0 + r) * HW + tx0) * CH;
#pragma unroll
        for (int it = 0; it < 2; ++it) {
            int p = it * 8 + pp;
            bf16x8 v = *(const bf16x8*)(bw + ((r * 2048 + p * 128 + jc * 16) ^ ((p & 7) << 4)));
            *(bf16x8*)(og + p * CH + jc * 8) = v;    // 1KB contiguous per instr
        }
    }

    // BN batch-stat partials: reduce over px lanes, stash, one atomic per ch
#pragma unroll
    for (int off = 1; off < 16; off <<= 1) {
#pragma unroll
        for (int m = 0; m < 4; ++m)
#pragma unroll
            for (int q = 0; q < 4; ++q) {
                s_[m][q] += __shfl_xor(s_[m][q], off);
                sq[m][q] += __shfl_xor(sq[m][q], off);
            }
    }
    float* red = (float*)(xt + 16384);        // byte 32768, past bounce regions
    if (px == 0) {
#pragma unroll
        for (int m = 0; m < 4; ++m)
#pragma unroll
            for (int q = 0; q < 4; ++q) {
                int c = m * 16 + kg * 4 + q;
                red[wave * 128 + c]      = s_[m][q];
                red[wave * 128 + 64 + c] = sq[m][q];
            }
    }
    __syncthreads();
    if (tid < 128) {
        float t = red[tid] + red[128 + tid] + red[256 + tid] + red[384 + tid];
        atomicAdd(&sums[tid], t);
    }
}

// w [b][co][ci][3][3] f32  ->  wt [b][tap][co][ci] bf16
__global__ __launch_bounds__(256)
void repack_kernel(const float* __restrict__ w, u16* __restrict__ wt)
{
    int i  = blockIdx.x * 256 + threadIdx.x;   // 32*9*64*64 = 1179648 exact
    int ci = i & 63;
    int co = (i >> 6) & 63;
    int bt = i >> 12;                          // b*9 + t
    int t  = bt % 9;
    int b  = bt / 9;
    wt[i] = f2b(w[(((size_t)b * 64 + co) * 64 + ci) * 9 + t]);
}

__global__ void bnparam_kernel(const float* __restrict__ sums,
                               const float* __restrict__ gamma,
                               const float* __restrict__ beta,
                               float* __restrict__ sb)
{
    int c = threadIdx.x;
    if (c < 64) {
        float mean = sums[c] * (1.f / NPC);
        float var  = sums[64 + c] * (1.f / NPC) - mean * mean;
        float sc   = gamma[c] * rsqrtf(var + 1e-5f);
        sb[c]      = sc;
        sb[64 + c] = beta[c] - mean * sc;
    }
}

__global__ void zero_kernel(float* __restrict__ p, int n)
{
    int i = blockIdx.x * 256 + threadIdx.x;
    if (i < n) p[i] = 0.f;
}

// out = relu(bn2(y2) + x); y2 [b][pix][c] bf16, x/out [b][c][pix] f32 (LDS transpose)
__global__ __launch_bounds__(256)
void finalize_kernel(const u16* __restrict__ y2, const float* __restrict__ x,
                     const float* __restrict__ sb, float* __restrict__ out)
{
    __shared__ float lt[64][33];
    const int b  = blockIdx.y;
    const int p0 = blockIdx.x * 32;
    const int t  = threadIdx.x;
    {
        int pi = t >> 3, cg = (t & 7) * 8;
        const u16* src = y2 + ((size_t)b * HW2 + p0 + pi) * CH + cg;
        bf16x8 v = *(const bf16x8*)src;
#pragma unroll
        for (int j = 0; j < 8; ++j)
            lt[cg + j][pi] = b2f((u16)v[j]) * sb[cg + j] + sb[64 + cg + j];
    }
    __syncthreads();
    {
        int c = t >> 2, xg = (t & 3) * 8;
        size_t base = ((size_t)b * CH + c) * HW2 + p0 + xg;
        float4 x0 = *(const float4*)(x + base);
        float4 x1 = *(const float4*)(x + base + 4);
        float4 r0, r1;
        r0.x = fmaxf(lt[c][xg + 0] + x0.x, 0.f);
        r0.y = fmaxf(lt[c][xg + 1] + x0.y, 0.f);
        r0.z = fmaxf(lt[c][xg + 2] + x0.z, 0.f);
        r0.w = fmaxf(lt[c][xg + 3] + x0.w, 0.f);
        r1.x = fmaxf(lt[c][xg + 4] + x1.x, 0.f);
        r1.y = fmaxf(lt[c][xg + 5] + x1.y, 0.f);
        r1.z = fmaxf(lt[c][xg + 6] + x1.z, 0.f);
        r1.w = fmaxf(lt[c][xg + 7] + x1.w, 0.f);
        *(float4*)(out + base)     = r0;
        *(float4*)(out + base + 4) = r1;
    }
}

extern "C" void kernel_launch(void* const* d_in, const int* in_sizes, int n_in,
                              void* d_out, int out_size, void* d_ws, size_t ws_size,
                              hipStream_t stream)
{
    const float* x  = (const float*)d_in[0];
    const float* w1 = (const float*)d_in[1];
    const float* w2 = (const float*)d_in[2];
    const float* g1 = (const float*)d_in[3];
    const float* b1 = (const float*)d_in[4];
    const float* g2 = (const float*)d_in[5];
    const float* b2 = (const float*)d_in[6];
    float* out = (float*)d_out;

    char* ws = (char*)d_ws;
    const size_t nElem = (size_t)NB * CH * HW2;        // 25,690,112
    u16*   out1  = (u16*)ws;                           // [0, 51.38 MB)
    u16*   out2  = (u16*)(ws + nElem * 2);             // [51.38, 102.76 MB)
    float* st    = (float*)(ws + nElem * 4);           // 512 floats
    float* sums1 = st, *sums2 = st + 128, *sb1 = st + 256, *sb2 = st + 384;
    u16*   wt1   = out2;                               // dead until conv2 writes out2
    u16*   wt2   = (u16*)d_out;                        // dead until finalize writes out

    zero_kernel<<<1, 256, 0, stream>>>(st, 256);
    repack_kernel<<<4608, 256, 0, stream>>>(w1, wt1);

    const int cgrid = NB * 49;                         // 1568 blocks
    conv_mfma<0><<<cgrid, 256, 0, stream>>>(x, nullptr, wt1, nullptr, out1, sums1);
    bnparam_kernel<<<1, 64, 0, stream>>>(sums1, g1, b1, sb1);

    repack_kernel<<<4608, 256, 0, stream>>>(w2, wt2);
    conv_mfma<1><<<cgrid, 256, 0, stream>>>(nullptr, out1, wt2, sb1, out2, sums2);
    bnparam_kernel<<<1, 64, 0, stream>>>(sums2, g2, b2, sb2);

    finalize_kernel<<<dim3(HW2 / 32, NB), 256, 0, stream>>>(out2, x, sb2, out);
}

// Round 5
// 229.844 us; speedup vs baseline: 1.3963x; 1.3963x over previous
//
#include <hip/hip_runtime.h>

// B=32, C=64, H=W=112. Per-sample 3x3 convs via bf16 MFMA implicit GEMM.
// Per sample GEMM: M=64 (cout), K=576 (cin*9), N=12544 (pixels).
// Block: 16x16 output tile, 4 waves x 4 rows. 18x18x64 halo tile + one
// 32-ci weight half in LDS (78336 B -> 2 blocks/CU). k-loop is pure LDS+MFMA.
#define HW    112
#define HW2   12544
#define CH    64
#define NB    32
#define TS    16
#define HP    18
#define NPIX  324           // 18*18 halo pixels
#define NPC   (NB*HW2)      // per-channel count for BN stats

using u16 = unsigned short;
typedef __attribute__((ext_vector_type(8))) short bf16x8;   // 8 bf16 = 4 VGPRs
typedef __attribute__((ext_vector_type(4))) float f32x4;

__device__ __forceinline__ float b2f(u16 u) {
    union { unsigned int i; float f; } c;
    c.i = ((unsigned int)u) << 16;
    return c.f;
}
__device__ __forceinline__ u16 f2b(float f) {
    union { float f; unsigned int i; } c;
    c.f = f;
    unsigned int x = c.i;
    x += 0x7fffu + ((x >> 16) & 1u);   // RNE
    return (u16)(x >> 16);
}

// Input tile: [pix][ci 0..63] bf16, 128 B per pixel row.
// XOR-swizzle byte bits 4-6 with pix&7: conflict-free ds_read/write_b128.
__device__ __forceinline__ int swz(int pix, int ci) {
    return (pix * 128 + ci * 2) ^ ((pix & 7) << 4);
}

// MODE 0: input = raw f32 x [b][ci][y][x]   (conv1)
// MODE 1: input = bf16 out1 [b][y][x][ci] with BN1 affine + ReLU fused (conv2)
// wt: bf16 [b][tap][co][ci]. out: bf16 [b][y][x][co]. sums: 128 floats (sum,sumsq).
template<int MODE>
__global__ __launch_bounds__(256, 2)
void conv_mfma(const float* __restrict__ xf, const u16* __restrict__ xb,
               const u16* __restrict__ wt, const float* __restrict__ sbp,
               u16* __restrict__ out, float* __restrict__ sums)
{
    __shared__ u16 xt[NPIX * CH];        // 41472 B input tile
    __shared__ u16 wl[9 * 4 * 64 * 8];   // 36864 B: [tap][kg][co][8ci] weight half
    // XCD swizzle: 1568 blocks = 8 XCD x 196; consecutive ids same sample.
    const int bid = (int)blockIdx.x;
    const int sid = (bid & 7) * 196 + (bid >> 3);
    const int b   = sid / 49;
    const int rem = sid - b * 49;
    const int ty0 = (rem / 7) * TS, tx0 = (rem % 7) * TS;
    const int tid  = threadIdx.x;
    const int lane = tid & 63, wave = tid >> 6;
    const int px = lane & 15, kg = lane >> 4;
    const int y0 = wave * 4;
    const u16* wtb = wt + (size_t)b * 9 * CH * CH;
    const int wco = tid & 63, wkg = tid >> 6;    // W-staging roles

    // ---- stage W ci-half 0: [tap][kg][co][8ci] <- wt[b][tap][co][kg*8..+8] ----
    {
        bf16x8 v[9];
#pragma unroll
        for (int c = 0; c < 9; ++c)
            v[c] = *(const bf16x8*)(wtb + c * 4096 + wco * 64 + wkg * 8);
#pragma unroll
        for (int c = 0; c < 9; ++c)
            *(bf16x8*)(wl + c * 2048 + tid * 8) = v[c];
    }

    // ---- stage 18x18x64 input tile into LDS (pixel-major, swizzled) ----
    if (MODE == 0) {
        for (int t = tid; t < NPIX * 8; t += 256) {
            int g  = t / NPIX;               // ci group (8 ci)
            int r  = t - g * NPIX;           // pixel in tile
            int iy = r / HP, ix = r - iy * HP;
            int gy = ty0 + iy - 1, gx = tx0 + ix - 1;
            bf16x8 pk = (bf16x8)0;
            if (((unsigned)gy < HW) && ((unsigned)gx < HW)) {
                const float* src = xf + ((size_t)b * CH + g * 8) * HW2 + gy * HW + gx;
#pragma unroll
                for (int j = 0; j < 8; ++j)
                    pk[j] = (short)f2b(src[(size_t)j * HW2]);
            }
            *(bf16x8*)((char*)xt + swz(r, g * 8)) = pk;
        }
    } else {
        const int j8 = (tid & 7) * 8;        // lane-fixed channel chunk
        float sc[8], bi[8];
#pragma unroll
        for (int e = 0; e < 8; ++e) { sc[e] = sbp[j8 + e]; bi[e] = sbp[64 + j8 + e]; }
        for (int t = tid; t < NPIX * 8; t += 256) {
            int p  = t >> 3;                 // pixel in tile
            int iy = p / HP, ix = p - iy * HP;
            int gy = ty0 + iy - 1, gx = tx0 + ix - 1;
            bf16x8 pk = (bf16x8)0;
            if (((unsigned)gy < HW) && ((unsigned)gx < HW)) {
                bf16x8 v = *(const bf16x8*)(xb + ((size_t)b * HW2 + (size_t)gy * HW + gx) * CH + j8);
#pragma unroll
                for (int e = 0; e < 8; ++e) {
                    float tv = b2f((u16)v[e]) * sc[e] + bi[e];
                    pk[e] = (short)f2b(tv > 0.f ? tv : 0.f);
                }
            }
            *(bf16x8*)((char*)xt + swz(p, j8)) = pk;
        }
    }
    __syncthreads();

    f32x4 acc[4][4];
#pragma unroll
    for (int r = 0; r < 4; ++r)
#pragma unroll
        for (int m = 0; m < 4; ++m) acc[r][m] = (f32x4)0.f;

    // ---- main loop: 2 ci-halves x 9 taps; pure LDS + MFMA ----
#pragma unroll
    for (int h = 0; h < 2; ++h) {
        if (h == 1) {
            __syncthreads();                 // all waves done with half 0
            bf16x8 v[9];
#pragma unroll
            for (int c = 0; c < 9; ++c)
                v[c] = *(const bf16x8*)(wtb + c * 4096 + wco * 64 + 32 + wkg * 8);
#pragma unroll
            for (int c = 0; c < 9; ++c)
                *(bf16x8*)(wl + c * 2048 + tid * 8) = v[c];
            __syncthreads();
        }
#pragma unroll
        for (int tap = 0; tap < 9; ++tap) {
            const int dy = tap / 3, dx = tap % 3;
            bf16x8 af[4];
#pragma unroll
            for (int m = 0; m < 4; ++m)
                af[m] = *(const bf16x8*)(wl + tap * 2048 + kg * 512 + (m * 16 + px) * 8);
#pragma unroll
            for (int r = 0; r < 4; ++r) {
                const int pr = (y0 + r + dy) * HP + px + dx;
                bf16x8 bfr = *(const bf16x8*)((const char*)xt + swz(pr, h * 32 + kg * 8));
#pragma unroll
                for (int m = 0; m < 4; ++m)
                    acc[r][m] = __builtin_amdgcn_mfma_f32_16x16x32_bf16(af[m], bfr, acc[r][m], 0, 0, 0);
            }
        }
    }
    __syncthreads();                         // xt free for reuse below

    // ---- epilogue: direct bf16 stores [b][y][x][co] + BN partials ----
    float s_[4][4], sq[4][4];
#pragma unroll
    for (int m = 0; m < 4; ++m)
#pragma unroll
        for (int q = 0; q < 4; ++q) { s_[m][q] = 0.f; sq[m][q] = 0.f; }

    const size_t obase = ((size_t)b * HW2 + (size_t)(ty0 + y0) * HW + tx0 + px) * CH + kg * 4;
#pragma unroll
    for (int r = 0; r < 4; ++r) {
#pragma unroll
        for (int m = 0; m < 4; ++m) {
            float v0 = acc[r][m][0], v1 = acc[r][m][1], v2 = acc[r][m][2], v3 = acc[r][m][3];
            s_[m][0] += v0; s_[m][1] += v1; s_[m][2] += v2; s_[m][3] += v3;
            sq[m][0] += v0 * v0; sq[m][1] += v1 * v1; sq[m][2] += v2 * v2; sq[m][3] += v3 * v3;
            uint2 pk;
            pk.x = ((unsigned)f2b(v1) << 16) | f2b(v0);
            pk.y = ((unsigned)f2b(v3) << 16) | f2b(v2);
            *(uint2*)(out + obase + (size_t)r * HW * CH + m * 16) = pk;
        }
    }
    // reduce partials across the 16 px lanes, stash, one atomic per channel
#pragma unroll
    for (int off = 1; off < 16; off <<= 1) {
#pragma unroll
        for (int m = 0; m < 4; ++m)
#pragma unroll
            for (int q = 0; q < 4; ++q) {
                s_[m][q] += __shfl_xor(s_[m][q], off);
                sq[m][q] += __shfl_xor(sq[m][q], off);
            }
    }
    float* red = (float*)xt;
    if (px == 0) {
#pragma unroll
        for (int m = 0; m < 4; ++m)
#pragma unroll
            for (int q = 0; q < 4; ++q) {
                int c = m * 16 + kg * 4 + q;
                red[wave * 128 + c]      = s_[m][q];
                red[wave * 128 + 64 + c] = sq[m][q];
            }
    }
    __syncthreads();
    if (tid < 128) {
        float t = red[tid] + red[128 + tid] + red[256 + tid] + red[384 + tid];
        atomicAdd(&sums[tid], t);
    }
}

// w [b][co][ci][3][3] f32  ->  wt [b][tap][co][ci] bf16
__global__ __launch_bounds__(256)
void repack_kernel(const float* __restrict__ w, u16* __restrict__ wt)
{
    int i  = blockIdx.x * 256 + threadIdx.x;   // 32*9*64*64 = 1179648 exact
    int ci = i & 63;
    int co = (i >> 6) & 63;
    int bt = i >> 12;                          // b*9 + t
    int t  = bt % 9;
    int b  = bt / 9;
    wt[i] = f2b(w[(((size_t)b * 64 + co) * 64 + ci) * 9 + t]);
}

__global__ void bnparam_kernel(const float* __restrict__ sums,
                               const float* __restrict__ gamma,
                               const float* __restrict__ beta,
                               float* __restrict__ sb)
{
    int c = threadIdx.x;
    if (c < 64) {
        float mean = sums[c] * (1.f / NPC);
        float var  = sums[64 + c] * (1.f / NPC) - mean * mean;
        float sc   = gamma[c] * rsqrtf(var + 1e-5f);
        sb[c]      = sc;
        sb[64 + c] = beta[c] - mean * sc;
    }
}

__global__ void zero_kernel(float* __restrict__ p, int n)
{
    int i = blockIdx.x * 256 + threadIdx.x;
    if (i < n) p[i] = 0.f;
}

// out = relu(bn2(y2) + x); y2 [b][pix][c] bf16, x/out [b][c][pix] f32 (LDS transpose)
__global__ __launch_bounds__(256)
void finalize_kernel(const u16* __restrict__ y2, const float* __restrict__ x,
                     const float* __restrict__ sb, float* __restrict__ out)
{
    __shared__ float lt[64][33];
    const int b  = blockIdx.y;
    const int p0 = blockIdx.x * 32;
    const int t  = threadIdx.x;
    {
        int pi = t >> 3, cg = (t & 7) * 8;
        const u16* src = y2 + ((size_t)b * HW2 + p0 + pi) * CH + cg;
        bf16x8 v = *(const bf16x8*)src;
#pragma unroll
        for (int j = 0; j < 8; ++j)
            lt[cg + j][pi] = b2f((u16)v[j]) * sb[cg + j] + sb[64 + cg + j];
    }
    __syncthreads();
    {
        int c = t >> 2, xg = (t & 3) * 8;
        size_t base = ((size_t)b * CH + c) * HW2 + p0 + xg;
        float4 x0 = *(const float4*)(x + base);
        float4 x1 = *(const float4*)(x + base + 4);
        float4 r0, r1;
        r0.x = fmaxf(lt[c][xg + 0] + x0.x, 0.f);
        r0.y = fmaxf(lt[c][xg + 1] + x0.y, 0.f);
        r0.z = fmaxf(lt[c][xg + 2] + x0.z, 0.f);
        r0.w = fmaxf(lt[c][xg + 3] + x0.w, 0.f);
        r1.x = fmaxf(lt[c][xg + 4] + x1.x, 0.f);
        r1.y = fmaxf(lt[c][xg + 5] + x1.y, 0.f);
        r1.z = fmaxf(lt[c][xg + 6] + x1.z, 0.f);
        r1.w = fmaxf(lt[c][xg + 7] + x1.w, 0.f);
        *(float4*)(out + base)     = r0;
        *(float4*)(out + base + 4) = r1;
    }
}

extern "C" void kernel_launch(void* const* d_in, const int* in_sizes, int n_in,
                              void* d_out, int out_size, void* d_ws, size_t ws_size,
                              hipStream_t stream)
{
    const float* x  = (const float*)d_in[0];
    const float* w1 = (const float*)d_in[1];
    const float* w2 = (const float*)d_in[2];
    const float* g1 = (const float*)d_in[3];
    const float* b1 = (const float*)d_in[4];
    const float* g2 = (const float*)d_in[5];
    const float* b2 = (const float*)d_in[6];
    float* out = (float*)d_out;

    char* ws = (char*)d_ws;
    const size_t nElem = (size_t)NB * CH * HW2;        // 25,690,112
    u16*   out1  = (u16*)ws;                           // [0, 51.38 MB)
    u16*   out2  = (u16*)(ws + nElem * 2);             // [51.38, 102.76 MB)
    float* st    = (float*)(ws + nElem * 4);           // 512 floats
    float* sums1 = st, *sums2 = st + 128, *sb1 = st + 256, *sb2 = st + 384;
    u16*   wt1   = out2;                               // dead until conv2 writes out2
    u16*   wt2   = (u16*)d_out;                        // dead until finalize writes out

    zero_kernel<<<1, 256, 0, stream>>>(st, 256);
    repack_kernel<<<4608, 256, 0, stream>>>(w1, wt1);

    const int cgrid = NB * 49;                         // 1568 blocks
    conv_mfma<0><<<cgrid, 256, 0, stream>>>(x, nullptr, wt1, nullptr, out1, sums1);
    bnparam_kernel<<<1, 64, 0, stream>>>(sums1, g1, b1, sb1);

    repack_kernel<<<4608, 256, 0, stream>>>(w2, wt2);
    conv_mfma<1><<<cgrid, 256, 0, stream>>>(nullptr, out1, wt2, sb1, out2, sums2);
    bnparam_kernel<<<1, 64, 0, stream>>>(sums2, g2, b2, sb2);

    finalize_kernel<<<dim3(HW2 / 32, NB), 256, 0, stream>>>(out2, x, sb2, out);
}

// Round 6
// 227.807 us; speedup vs baseline: 1.4088x; 1.0089x over previous
//
#include <hip/hip_runtime.h>

// B=32, C=64, H=W=112. Per-sample 3x3 convs via bf16 MFMA implicit GEMM.
// Per sample GEMM: M=64 (cout), K=576 (cin*9), N=12544 (pixels).
// Block: 16x16 output tile, 8 waves x 2 rows (512 thr). 18x18x64 halo tile +
// one 32-ci weight half in LDS (78336 B -> 2 blocks/CU -> 4 waves/SIMD).
#define HW    112
#define HW2   12544
#define CH    64
#define TS    16
#define HP    18
#define NPIX  324           // 18*18 halo pixels
#define NB    32
#define NPC   (NB*HW2)      // per-channel count for BN stats

using u16 = unsigned short;
typedef __attribute__((ext_vector_type(8))) short bf16x8;   // 8 bf16 = 4 VGPRs
typedef __attribute__((ext_vector_type(4))) float f32x4;

__device__ __forceinline__ float b2f(u16 u) {
    union { unsigned int i; float f; } c;
    c.i = ((unsigned int)u) << 16;
    return c.f;
}
__device__ __forceinline__ u16 f2b(float f) {
    union { float f; unsigned int i; } c;
    c.f = f;
    unsigned int x = c.i;
    x += 0x7fffu + ((x >> 16) & 1u);   // RNE
    return (u16)(x >> 16);
}

// Input tile: [pix][ci 0..63] bf16, 128 B per pixel row.
// XOR-swizzle byte bits 4-6 with pix&7: conflict-free ds_read/write_b128.
__device__ __forceinline__ int swz(int pix, int ci) {
    return (pix * 128 + ci * 2) ^ ((pix & 7) << 4);
}

// MODE 0: input = raw f32 x [b][ci][y][x]   (conv1)
// MODE 1: input = bf16 out1 [b][y][x][ci] with BN1 affine + ReLU fused (conv2)
// wt: bf16 [b][tap][co][ci]. out: bf16 [b][y][x][co]. sums: 128 floats (sum,sumsq).
template<int MODE>
__global__ __launch_bounds__(512, 4)
void conv_mfma(const float* __restrict__ xf, const u16* __restrict__ xb,
               const u16* __restrict__ wt, const float* __restrict__ sbp,
               u16* __restrict__ out, float* __restrict__ sums)
{
    __shared__ u16 xt[NPIX * CH];        // 41472 B input tile
    __shared__ u16 wl[9 * 4 * 64 * 8];   // 36864 B: [tap][kg][co][8ci] weight half
    // XCD swizzle: 1568 blocks = 8 XCD x 196; consecutive ids same sample.
    const int bid = (int)blockIdx.x;
    const int sid = (bid & 7) * 196 + (bid >> 3);
    const int b   = sid / 49;
    const int rem = sid - b * 49;
    const int ty0 = (rem / 7) * TS, tx0 = (rem % 7) * TS;
    const int tid  = threadIdx.x;
    const int lane = tid & 63, wave = tid >> 6;
    const int px = lane & 15, kg = lane >> 4;
    const int y0 = wave * 2;
    const u16* wtb = wt + (size_t)b * 9 * CH * CH;
    const int wco = tid & 63, wkg = (tid >> 6) & 3, wt9 = tid >> 8; // W-staging roles

    // ---- stage W ci-half 0: [tap][kg][co][8ci] <- wt[b][tap][co][kg*8..+8] ----
    for (int c = wt9; c < 9; c += 2) {
        bf16x8 v = *(const bf16x8*)(wtb + c * 4096 + wco * 64 + wkg * 8);
        *(bf16x8*)(wl + c * 2048 + (tid & 255) * 8) = v;
    }

    // ---- stage 18x18x64 input tile into LDS (pixel-major, swizzled) ----
    if (MODE == 0) {
        for (int t = tid; t < NPIX * 8; t += 512) {
            int g  = t / NPIX;               // ci group (8 ci)
            int r  = t - g * NPIX;           // pixel in tile
            int iy = r / HP, ix = r - iy * HP;
            int gy = ty0 + iy - 1, gx = tx0 + ix - 1;
            bf16x8 pk = (bf16x8)0;
            if (((unsigned)gy < HW) && ((unsigned)gx < HW)) {
                const float* src = xf + ((size_t)b * CH + g * 8) * HW2 + gy * HW + gx;
#pragma unroll
                for (int j = 0; j < 8; ++j)
                    pk[j] = (short)f2b(src[(size_t)j * HW2]);
            }
            *(bf16x8*)((char*)xt + swz(r, g * 8)) = pk;
        }
    } else {
        const int j8 = (tid & 7) * 8;        // lane-fixed channel chunk
        float sc[8], bi[8];
#pragma unroll
        for (int e = 0; e < 8; ++e) { sc[e] = sbp[j8 + e]; bi[e] = sbp[64 + j8 + e]; }
        for (int t = tid; t < NPIX * 8; t += 512) {
            int p  = t >> 3;                 // pixel in tile (t&7 == tid&7 invariant)
            int iy = p / HP, ix = p - iy * HP;
            int gy = ty0 + iy - 1, gx = tx0 + ix - 1;
            bf16x8 pk = (bf16x8)0;
            if (((unsigned)gy < HW) && ((unsigned)gx < HW)) {
                bf16x8 v = *(const bf16x8*)(xb + ((size_t)b * HW2 + (size_t)gy * HW + gx) * CH + j8);
#pragma unroll
                for (int e = 0; e < 8; ++e) {
                    float tv = b2f((u16)v[e]) * sc[e] + bi[e];
                    pk[e] = (short)f2b(tv > 0.f ? tv : 0.f);
                }
            }
            *(bf16x8*)((char*)xt + swz(p, j8)) = pk;
        }
    }
    __syncthreads();

    f32x4 acc[2][4];
#pragma unroll
    for (int r = 0; r < 2; ++r)
#pragma unroll
        for (int m = 0; m < 4; ++m) acc[r][m] = (f32x4)0.f;

    // ---- main loop: 2 ci-halves x 9 taps; pure LDS + MFMA ----
#pragma unroll
    for (int h = 0; h < 2; ++h) {
        if (h == 1) {
            __syncthreads();                 // all waves done with half 0
            for (int c = wt9; c < 9; c += 2) {
                bf16x8 v = *(const bf16x8*)(wtb + c * 4096 + wco * 64 + 32 + wkg * 8);
                *(bf16x8*)(wl + c * 2048 + (tid & 255) * 8) = v;
            }
            __syncthreads();
        }
#pragma unroll
        for (int tap = 0; tap < 9; ++tap) {
            const int dy = tap / 3, dx = tap % 3;
            bf16x8 af[4];
#pragma unroll
            for (int m = 0; m < 4; ++m)
                af[m] = *(const bf16x8*)(wl + tap * 2048 + kg * 512 + (m * 16 + px) * 8);
#pragma unroll
            for (int r = 0; r < 2; ++r) {
                const int pr = (y0 + r + dy) * HP + px + dx;
                bf16x8 bfr = *(const bf16x8*)((const char*)xt + swz(pr, h * 32 + kg * 8));
#pragma unroll
                for (int m = 0; m < 4; ++m)
                    acc[r][m] = __builtin_amdgcn_mfma_f32_16x16x32_bf16(af[m], bfr, acc[r][m], 0, 0, 0);
            }
        }
    }
    __syncthreads();                         // xt free for reuse below

    // ---- epilogue: direct bf16 stores [b][y][x][co] + BN partials ----
    float s_[4][4], sq[4][4];
#pragma unroll
    for (int m = 0; m < 4; ++m)
#pragma unroll
        for (int q = 0; q < 4; ++q) { s_[m][q] = 0.f; sq[m][q] = 0.f; }

    const size_t obase = ((size_t)b * HW2 + (size_t)(ty0 + y0) * HW + tx0 + px) * CH + kg * 4;
#pragma unroll
    for (int r = 0; r < 2; ++r) {
#pragma unroll
        for (int m = 0; m < 4; ++m) {
            float v0 = acc[r][m][0], v1 = acc[r][m][1], v2 = acc[r][m][2], v3 = acc[r][m][3];
            s_[m][0] += v0; s_[m][1] += v1; s_[m][2] += v2; s_[m][3] += v3;
            sq[m][0] += v0 * v0; sq[m][1] += v1 * v1; sq[m][2] += v2 * v2; sq[m][3] += v3 * v3;
            uint2 pk;
            pk.x = ((unsigned)f2b(v1) << 16) | f2b(v0);
            pk.y = ((unsigned)f2b(v3) << 16) | f2b(v2);
            *(uint2*)(out + obase + (size_t)r * HW * CH + m * 16) = pk;
        }
    }
    // reduce partials across the 16 px lanes, stash, one atomic per channel
#pragma unroll
    for (int off = 1; off < 16; off <<= 1) {
#pragma unroll
        for (int m = 0; m < 4; ++m)
#pragma unroll
            for (int q = 0; q < 4; ++q) {
                s_[m][q] += __shfl_xor(s_[m][q], off);
                sq[m][q] += __shfl_xor(sq[m][q], off);
            }
    }
    float* red = (float*)xt;                 // 8 waves x 128 floats = 4KB
    if (px == 0) {
#pragma unroll
        for (int m = 0; m < 4; ++m)
#pragma unroll
            for (int q = 0; q < 4; ++q) {
                int c = m * 16 + kg * 4 + q;
                red[wave * 128 + c]      = s_[m][q];
                red[wave * 128 + 64 + c] = sq[m][q];
            }
    }
    __syncthreads();
    if (tid < 128) {
        float t = 0.f;
#pragma unroll
        for (int k = 0; k < 8; ++k) t += red[k * 128 + tid];
        atomicAdd(&sums[tid], t);
    }
}

// w [b][co][ci][3][3] f32  ->  wt [b][tap][co][ci] bf16
__global__ __launch_bounds__(256)
void repack_kernel(const float* __restrict__ w, u16* __restrict__ wt)
{
    int i  = blockIdx.x * 256 + threadIdx.x;   // 32*9*64*64 = 1179648 exact
    int ci = i & 63;
    int co = (i >> 6) & 63;
    int bt = i >> 12;                          // b*9 + t
    int t  = bt % 9;
    int b  = bt / 9;
    wt[i] = f2b(w[(((size_t)b * 64 + co) * 64 + ci) * 9 + t]);
}

__global__ void bnparam_kernel(const float* __restrict__ sums,
                               const float* __restrict__ gamma,
                               const float* __restrict__ beta,
                               float* __restrict__ sb)
{
    int c = threadIdx.x;
    if (c < 64) {
        float mean = sums[c] * (1.f / NPC);
        float var  = sums[64 + c] * (1.f / NPC) - mean * mean;
        float sc   = gamma[c] * rsqrtf(var + 1e-5f);
        sb[c]      = sc;
        sb[64 + c] = beta[c] - mean * sc;
    }
}

__global__ void zero_kernel(float* __restrict__ p, int n)
{
    int i = blockIdx.x * 256 + threadIdx.x;
    if (i < n) p[i] = 0.f;
}

// out = relu(bn2(y2) + x); y2 [b][pix][c] bf16, x/out [b][c][pix] f32 (LDS transpose)
__global__ __launch_bounds__(256)
void finalize_kernel(const u16* __restrict__ y2, const float* __restrict__ x,
                     const float* __restrict__ sb, float* __restrict__ out)
{
    __shared__ float lt[64][33];
    const int b  = blockIdx.y;
    const int p0 = blockIdx.x * 32;
    const int t  = threadIdx.x;
    {
        int pi = t >> 3, cg = (t & 7) * 8;
        const u16* src = y2 + ((size_t)b * HW2 + p0 + pi) * CH + cg;
        bf16x8 v = *(const bf16x8*)src;
#pragma unroll
        for (int j = 0; j < 8; ++j)
            lt[cg + j][pi] = b2f((u16)v[j]) * sb[cg + j] + sb[64 + cg + j];
    }
    __syncthreads();
    {
        int c = t >> 2, xg = (t & 3) * 8;
        size_t base = ((size_t)b * CH + c) * HW2 + p0 + xg;
        float4 x0 = *(const float4*)(x + base);
        float4 x1 = *(const float4*)(x + base + 4);
        float4 r0, r1;
        r0.x = fmaxf(lt[c][xg + 0] + x0.x, 0.f);
        r0.y = fmaxf(lt[c][xg + 1] + x0.y, 0.f);
        r0.z = fmaxf(lt[c][xg + 2] + x0.z, 0.f);
        r0.w = fmaxf(lt[c][xg + 3] + x0.w, 0.f);
        r1.x = fmaxf(lt[c][xg + 4] + x1.x, 0.f);
        r1.y = fmaxf(lt[c][xg + 5] + x1.y, 0.f);
        r1.z = fmaxf(lt[c][xg + 6] + x1.z, 0.f);
        r1.w = fmaxf(lt[c][xg + 7] + x1.w, 0.f);
        *(float4*)(out + base)     = r0;
        *(float4*)(out + base + 4) = r1;
    }
}

extern "C" void kernel_launch(void* const* d_in, const int* in_sizes, int n_in,
                              void* d_out, int out_size, void* d_ws, size_t ws_size,
                              hipStream_t stream)
{
    const float* x  = (const float*)d_in[0];
    const float* w1 = (const float*)d_in[1];
    const float* w2 = (const float*)d_in[2];
    const float* g1 = (const float*)d_in[3];
    const float* b1 = (const float*)d_in[4];
    const float* g2 = (const float*)d_in[5];
    const float* b2 = (const float*)d_in[6];
    float* out = (float*)d_out;

    char* ws = (char*)d_ws;
    const size_t nElem = (size_t)NB * CH * HW2;        // 25,690,112
    u16*   out1  = (u16*)ws;                           // [0, 51.38 MB)
    u16*   out2  = (u16*)(ws + nElem * 2);             // [51.38, 102.76 MB)
    float* st    = (float*)(ws + nElem * 4);           // 512 floats
    float* sums1 = st, *sums2 = st + 128, *sb1 = st + 256, *sb2 = st + 384;
    u16*   wt1   = out2;                               // dead until conv2 writes out2
    u16*   wt2   = (u16*)d_out;                        // dead until finalize writes out

    zero_kernel<<<1, 256, 0, stream>>>(st, 256);
    repack_kernel<<<4608, 256, 0, stream>>>(w1, wt1);

    const int cgrid = NB * 49;                         // 1568 blocks
    conv_mfma<0><<<cgrid, 512, 0, stream>>>(x, nullptr, wt1, nullptr, out1, sums1);
    bnparam_kernel<<<1, 64, 0, stream>>>(sums1, g1, b1, sb1);

    repack_kernel<<<4608, 256, 0, stream>>>(w2, wt2);
    conv_mfma<1><<<cgrid, 512, 0, stream>>>(nullptr, out1, wt2, sb1, out2, sums2);
    bnparam_kernel<<<1, 64, 0, stream>>>(sums2, g2, b2, sb2);

    finalize_kernel<<<dim3(HW2 / 32, NB), 256, 0, stream>>>(out2, x, sb2, out);
}